// Round 5
// baseline (278.184 us; speedup 1.0000x reference)
//
#include <hip/hip_runtime.h>
#include <hip/hip_bf16.h>

typedef __attribute__((ext_vector_type(8))) short short8;
typedef __attribute__((ext_vector_type(4))) float f32x4;

__device__ __forceinline__ float b2f(short s) {
    return __uint_as_float(((unsigned int)(unsigned short)s) << 16);
}
__device__ __forceinline__ short f2b(float f) {
    unsigned int u = __float_as_uint(f);
    u += 0x7fffu + ((u >> 16) & 1u);       // RNE
    return (short)(u >> 16);
}
__device__ __forceinline__ unsigned pack2(float a, float b) {
    return (unsigned)(unsigned short)f2b(a) | ((unsigned)(unsigned short)f2b(b) << 16);
}

// ============================================================================
// K0: one-off prep (~3us).
//   ucotT[co][r]   = bf16(Uco[r][co])            (4096)  - legacy k2 fallback
//   ucinT[r][c]    = bf16(Ucin[c][r])            (2048)  - k1 MFMA A-operand
//   gk[k][co][r]   = bf16(Ukd[k][r]*Uco[r][co])  (12288) - d-conv folded into
//                    the out-GEMM: out[d,co] = sum_k sum_r s[d+k,r]*G_k[r,co]
// ============================================================================
__global__ __launch_bounds__(64)
void k0_prep(const float* __restrict__ Uco, const float* __restrict__ Ucin,
             const float* __restrict__ Ukd,
             short* __restrict__ ucotT, short* __restrict__ ucinT,
             short* __restrict__ gk)
{
    const int i = blockIdx.x * 64 + threadIdx.x;    // 0..18431
    if (i < 4096) {
        int co = i >> 6, r = i & 63;
        ucotT[co * 64 + r] = f2b(Uco[r * 64 + co]);
    } else if (i < 6144) {
        int j = i - 4096;                           // 0..2047
        int r = j >> 5, c = j & 31;
        ucinT[r * 32 + c] = f2b(Ucin[c * 64 + r]);
    } else if (i < 18432) {
        int j = i - 6144;                           // 0..12287
        int k = j >> 12, rem = j & 4095;
        int co = rem >> 6, r = rem & 63;
        gk[j] = f2b(Ukd[k * 64 + r] * Uco[r * 64 + co]);
    }
}

// ============================================================================
// K1 (unchanged from round 4): channel contraction as MFMA GEMM.
// ============================================================================
__global__ __launch_bounds__(256)
void k1_channel(const float* __restrict__ x,
                const float* __restrict__ Ucin,
                const short* __restrict__ ucinT_g,   // may be null
                short* __restrict__ t)
{
    __shared__ short xs[256 * 32];    // 16 KB  x^T tile, swizzled 16B slots
    __shared__ short uci[64 * 32];    //  4 KB  Ucin^T [r][c], linear

    const int tid = threadIdx.x;
    const int gp0 = blockIdx.x * 256;              // 2048 blocks, same b per block
    const int b   = gp0 >> 18;
    const int sp  = (gp0 & 262143) + tid;
    const float* xp = x + ((long)b << 23) + sp;

    if (ucinT_g) {
        ((short8*)uci)[tid] = ((const short8*)ucinT_g)[tid];
    } else {
        for (int i = tid; i < 2048; i += 256) {
            int r = i >> 5, c = i & 31;
            uci[i] = f2b(Ucin[c * 64 + r]);
        }
    }

    {
        float v[32];
#pragma unroll
        for (int c = 0; c < 32; ++c) v[c] = xp[(long)c << 18];
        const int swz = (tid >> 1) & 3;
#pragma unroll
        for (int oct = 0; oct < 4; ++oct) {
            short8 o;
#pragma unroll
            for (int j = 0; j < 8; ++j) o[j] = f2b(v[oct * 8 + j]);
            *(short8*)&xs[tid * 32 + ((oct ^ swz) << 3)] = o;
        }
    }
    __syncthreads();

    const int lane = tid & 63, wv = tid >> 6;
    const int l15 = lane & 15, quad = lane >> 4;

    short8 afr[4];
#pragma unroll
    for (int mt = 0; mt < 4; ++mt)
        afr[mt] = *(const short8*)&uci[(mt * 16 + l15) * 32 + quad * 8];

    f32x4 acc[4][4] = {};
#pragma unroll
    for (int nt = 0; nt < 4; ++nt) {
        const int srow = wv * 64 + nt * 16 + l15;
        const int slot = quad ^ ((srow >> 1) & 3);
        short8 bfr = *(const short8*)&xs[srow * 32 + (slot << 3)];
#pragma unroll
        for (int mt = 0; mt < 4; ++mt)
            acc[mt][nt] = __builtin_amdgcn_mfma_f32_16x16x32_bf16(
                afr[mt], bfr, acc[mt][nt], 0, 0, 0);
    }

#pragma unroll
    for (int nt = 0; nt < 4; ++nt) {
        const int srow = wv * 64 + nt * 16 + l15;
        short* tb = t + ((size_t)(gp0 + srow) << 6);
#pragma unroll
        for (int mt = 0; mt < 4; ++mt) {
            uint2 o;
            o.x = pack2(acc[mt][nt][0], acc[mt][nt][1]);
            o.y = pack2(acc[mt][nt][2], acc[mt][nt][3]);
            *(uint2*)&tb[mt * 16 + quad * 4] = o;
        }
    }
}

// ============================================================================
// K2 (round-5 rewrite): d-conv folded into the out-GEMM via G_k.
//   phase A: hw-conv (unchanged structure) -> s[66][72] bf16
//            stride 72 shorts: uint2 writes 8B-aligned + even-bank b128 reads
//   phase C: out[d][co] = sum_{k=0..2} sum_r s[d+k][r] * G_k[r][co]
//            wave wv owns co-slice nt=wv (16 cos) x all 64 d:
//            - 6 B-frags (3k x 2 r-halves) loaded ONCE per wave from L2-
//              resident gk (24 KB grid-wide) -> no LDS staging, no ucot
//            - 24 A-frag ds_read_b128 + 24 MFMA + bias + float4 stores
//   Removes: phase B (d-conv VALU pass), p + ucot LDS (27KB -> 9.5KB),
//            one __syncthreads, per-block ucot staging.
// ============================================================================
__global__ __launch_bounds__(256)
void k2_conv_gemm_gk(const short* __restrict__ t,
                     const float* __restrict__ Ukh,
                     const float* __restrict__ Ukw,
                     const float* __restrict__ bias,
                     const short* __restrict__ gk,
                     float* __restrict__ out)
{
    __shared__ short s[66 * 72];      //  9504 B

    const int tid = threadIdx.x;

    const int bid  = blockIdx.x;              // 8192 = 2b * 64h * 64w
    const int slot = bid & 7;
    const int idx  = bid >> 3;                // 1024 per slot
    const int b    = idx >> 9;
    const int rem  = idx & 511;
    const int h    = slot * 8 + (rem >> 6);
    const int w    = rem & 63;

    const int lane = tid & 63, wv = tid >> 6;
    const int l15 = lane & 15, quad = lane >> 4;
    const int co  = wv * 16 + l15;

    // prefetch this wave's 6 B-fragments (consumed after the barrier) + bias
    short8 bfr[3][2];
#pragma unroll
    for (int k = 0; k < 3; ++k)
#pragma unroll
        for (int rh = 0; rh < 2; ++rh)
            bfr[k][rh] = *(const short8*)&gk[(k * 64 + co) * 64 + rh * 32 + quad * 8];
    const float bs = bias[co];

    // 9 neighbor-column base pointers (element (d,r) at base + d*64 + r).
    const short* colp[9];
    bool valid[9];
#pragma unroll
    for (int kh = 0; kh < 3; ++kh) {
#pragma unroll
        for (int kw = 0; kw < 3; ++kw) {
            int hh = h + kh - 1, ww = w + kw - 1;
            bool v = ((unsigned)hh < 64u) && ((unsigned)ww < 64u);
            valid[kh * 3 + kw] = v;
            long base = v ? ((long)(b * 262144 + hh * 4096 + ww * 64) << 6) : 0;
            colp[kh * 3 + kw] = t + base;
        }
    }

    // ---- phase A: hw-conv. thread owns r-quad rq (fixed), iterates sd ----
    const int rq = tid & 15;                  // r = 4*rq .. 4*rq+3
    float4 W[9];
    {
        float4 a[3], c[3];
#pragma unroll
        for (int k = 0; k < 3; ++k) {
            a[k] = *(const float4*)&Ukh[k * 64 + 4 * rq];
            c[k] = *(const float4*)&Ukw[k * 64 + 4 * rq];
        }
#pragma unroll
        for (int kh = 0; kh < 3; ++kh)
#pragma unroll
            for (int kw = 0; kw < 3; ++kw) {
                int kk = kh * 3 + kw;
                float m = valid[kk] ? 1.f : 0.f;
                W[kk].x = a[kh].x * c[kw].x * m;
                W[kk].y = a[kh].y * c[kw].y * m;
                W[kk].z = a[kh].z * c[kw].z * m;
                W[kk].w = a[kh].w * c[kw].w * m;
            }
    }

    // zero edge rows sd=0 (d=-1) and sd=65 (d=64)
    if (tid < 32) {
        int sd = (tid < 16) ? 0 : 65;
        int rr = tid & 15;
        uint2 z; z.x = 0u; z.y = 0u;
        *(uint2*)&s[sd * 72 + 4 * rr] = z;
    }

    // main: 1024 in-bounds items = exactly 4/thread, software-pipelined
    {
        const int off0 = (tid >> 4) * 64 + 4 * rq;
        uint2 cur[9];
#pragma unroll
        for (int kk = 0; kk < 9; ++kk)
            cur[kk] = *(const uint2*)(colp[kk] + off0);

#pragma unroll
        for (int j = 0; j < 4; ++j) {
            uint2 nxt[9];
            if (j < 3) {
#pragma unroll
                for (int kk = 0; kk < 9; ++kk)
                    nxt[kk] = *(const uint2*)(colp[kk] + off0 + 1024 * (j + 1));
            }
            float a0 = 0.f, a1 = 0.f, a2 = 0.f, a3 = 0.f;
#pragma unroll
            for (int kk = 0; kk < 9; ++kk) {
                uint2 uu = cur[kk];
                a0 += W[kk].x * b2f((short)(uu.x));
                a1 += W[kk].y * b2f((short)(uu.x >> 16));
                a2 += W[kk].z * b2f((short)(uu.y));
                a3 += W[kk].w * b2f((short)(uu.y >> 16));
            }
            int sd = 1 + (tid >> 4) + 16 * j;
            uint2 o; o.x = pack2(a0, a1); o.y = pack2(a2, a3);
            *(uint2*)&s[sd * 72 + 4 * rq] = o;
            if (j < 3) {
#pragma unroll
                for (int kk = 0; kk < 9; ++kk) cur[kk] = nxt[kk];
            }
        }
    }
    __syncthreads();

    // ---- phase C: out GEMM with folded d-conv ----
    // acc[mt]: D rows d = mt*16 + quad*4 + i, col co = wv*16 + l15.
    // A-frag(mt,k,rh) rows m = mt*16 + l15 -> s[sd = m + k] (sd = d+1 shift
    // already built into s: out d needs s rows d..d+2 -> sd = d+k).
    f32x4 acc[4] = {};
#pragma unroll
    for (int mt = 0; mt < 4; ++mt) {
#pragma unroll
        for (int k = 0; k < 3; ++k) {
            const int row = mt * 16 + l15 + k;
#pragma unroll
            for (int rh = 0; rh < 2; ++rh) {
                short8 afr = *(const short8*)&s[row * 72 + rh * 32 + quad * 8];
                acc[mt] = __builtin_amdgcn_mfma_f32_16x16x32_bf16(
                    afr, bfr[k][rh], acc[mt], 0, 0, 0);
            }
        }
    }

#pragma unroll
    for (int mt = 0; mt < 4; ++mt) {
        int d = mt * 16 + quad * 4;
        float4 o;
        o.x = acc[mt][0] + bs; o.y = acc[mt][1] + bs;
        o.z = acc[mt][2] + bs; o.w = acc[mt][3] + bs;
        long addr = ((long)(b * 64 + co) << 18) + (h << 12) + (w << 6) + d;
        *(float4*)&out[addr] = o;
    }
}

// ============================================================================
// K2 legacy (round-3/4 version): used only if workspace lacks room for gk.
// ============================================================================
__global__ __launch_bounds__(256)
void k2_conv_gemm(const short* __restrict__ t,
                  const float* __restrict__ Ukh,
                  const float* __restrict__ Ukw,
                  const float* __restrict__ Ukd,
                  const float* __restrict__ Uco,
                  const float* __restrict__ bias,
                  const short* __restrict__ ucotT,   // may be null
                  float* __restrict__ out)
{
    __shared__ short s[66 * 64];
    __shared__ short p[64 * 72];
    __shared__ short ucot[64 * 72];

    const int tid = threadIdx.x;
    const int bid  = blockIdx.x;
    const int slot = bid & 7;
    const int idx  = bid >> 3;
    const int b    = idx >> 9;
    const int rem  = idx & 511;
    const int h    = slot * 8 + (rem >> 6);
    const int w    = rem & 63;

    const short* colp[9];
    bool valid[9];
#pragma unroll
    for (int kh = 0; kh < 3; ++kh) {
#pragma unroll
        for (int kw = 0; kw < 3; ++kw) {
            int hh = h + kh - 1, ww = w + kw - 1;
            bool v = ((unsigned)hh < 64u) && ((unsigned)ww < 64u);
            valid[kh * 3 + kw] = v;
            long base = v ? ((long)(b * 262144 + hh * 4096 + ww * 64) << 6) : 0;
            colp[kh * 3 + kw] = t + base;
        }
    }

    if (ucotT) {
        for (int i = tid; i < 512; i += 256) {
            int co = i >> 3, rb = i & 7;
            short8 v = *(const short8*)&ucotT[co * 64 + rb * 8];
            *(short8*)&ucot[co * 72 + rb * 8] = v;
        }
    } else {
        for (int i = tid; i < 4096; i += 256) {
            int r = i >> 6, co = i & 63;
            ucot[co * 72 + r] = f2b(Uco[i]);
        }
    }

    const int rq = tid & 15;
    float4 W[9];
    {
        float4 a[3], c[3];
#pragma unroll
        for (int k = 0; k < 3; ++k) {
            a[k] = *(const float4*)&Ukh[k * 64 + 4 * rq];
            c[k] = *(const float4*)&Ukw[k * 64 + 4 * rq];
        }
#pragma unroll
        for (int kh = 0; kh < 3; ++kh)
#pragma unroll
            for (int kw = 0; kw < 3; ++kw) {
                int kk = kh * 3 + kw;
                float m = valid[kk] ? 1.f : 0.f;
                W[kk].x = a[kh].x * c[kw].x * m;
                W[kk].y = a[kh].y * c[kw].y * m;
                W[kk].z = a[kh].z * c[kw].z * m;
                W[kk].w = a[kh].w * c[kw].w * m;
            }
    }

    if (tid < 32) {
        int sd = (tid < 16) ? 0 : 65;
        int rr = tid & 15;
        uint2 z; z.x = 0u; z.y = 0u;
        *(uint2*)&s[sd * 64 + 4 * rr] = z;
    }

    {
        const int off0 = (tid >> 4) * 64 + 4 * rq;
        uint2 cur[9];
#pragma unroll
        for (int kk = 0; kk < 9; ++kk)
            cur[kk] = *(const uint2*)(colp[kk] + off0);

#pragma unroll
        for (int j = 0; j < 4; ++j) {
            uint2 nxt[9];
            if (j < 3) {
#pragma unroll
                for (int kk = 0; kk < 9; ++kk)
                    nxt[kk] = *(const uint2*)(colp[kk] + off0 + 1024 * (j + 1));
            }
            float a0 = 0.f, a1 = 0.f, a2 = 0.f, a3 = 0.f;
#pragma unroll
            for (int kk = 0; kk < 9; ++kk) {
                uint2 uu = cur[kk];
                a0 += W[kk].x * b2f((short)(uu.x));
                a1 += W[kk].y * b2f((short)(uu.x >> 16));
                a2 += W[kk].z * b2f((short)(uu.y));
                a3 += W[kk].w * b2f((short)(uu.y >> 16));
            }
            int sd = 1 + (tid >> 4) + 16 * j;
            uint2 o; o.x = pack2(a0, a1); o.y = pack2(a2, a3);
            *(uint2*)&s[sd * 64 + 4 * rq] = o;
            if (j < 3) {
#pragma unroll
                for (int kk = 0; kk < 9; ++kk) cur[kk] = nxt[kk];
            }
        }
    }
    __syncthreads();

    {
        float4 Wd[3];
#pragma unroll
        for (int k = 0; k < 3; ++k)
            Wd[k] = *(const float4*)&Ukd[k * 64 + 4 * rq];
        for (int u = tid; u < 64 * 16; u += 256) {
            int d = u >> 4;
            float a0 = 0.f, a1 = 0.f, a2 = 0.f, a3 = 0.f;
#pragma unroll
            for (int k = 0; k < 3; ++k) {
                uint2 uu = *(const uint2*)&s[(d + k) * 64 + 4 * rq];
                a0 += Wd[k].x * b2f((short)(uu.x));
                a1 += Wd[k].y * b2f((short)(uu.x >> 16));
                a2 += Wd[k].z * b2f((short)(uu.y));
                a3 += Wd[k].w * b2f((short)(uu.y >> 16));
            }
            uint2 o; o.x = pack2(a0, a1); o.y = pack2(a2, a3);
            *(uint2*)&p[d * 72 + 4 * rq] = o;
        }
    }
    __syncthreads();

    {
        const int lane = tid & 63, wv = tid >> 6;
        const int l15 = lane & 15, quad = lane >> 4;
        short8 afr0 = *(const short8*)&p[(wv * 16 + l15) * 72 + quad * 8];
        short8 afr1 = *(const short8*)&p[(wv * 16 + l15) * 72 + 32 + quad * 8];
        f32x4 acc[4] = {};
#pragma unroll
        for (int nt = 0; nt < 4; ++nt) {
            short8 b0 = *(const short8*)&ucot[(nt * 16 + l15) * 72 + quad * 8];
            short8 b1 = *(const short8*)&ucot[(nt * 16 + l15) * 72 + 32 + quad * 8];
            acc[nt] = __builtin_amdgcn_mfma_f32_16x16x32_bf16(afr0, b0, acc[nt], 0, 0, 0);
            acc[nt] = __builtin_amdgcn_mfma_f32_16x16x32_bf16(afr1, b1, acc[nt], 0, 0, 0);
        }
#pragma unroll
        for (int nt = 0; nt < 4; ++nt) {
            int co = nt * 16 + l15;
            float bs = bias[co];
            int d = wv * 16 + quad * 4;
            float4 o;
            o.x = acc[nt][0] + bs; o.y = acc[nt][1] + bs;
            o.z = acc[nt][2] + bs; o.w = acc[nt][3] + bs;
            long addr = ((long)(b * 64 + co) << 18) + (h << 12) + (w << 6) + d;
            *(float4*)&out[addr] = o;
        }
    }
}

// ============================================================================
// Fallback (fused kernel) if workspace is too small for t.
// ============================================================================
#define NTH 512
#define NPADP 656
#define SMEM_BYTES ((NPADP*32 + NPADP*32 + 432*32 + 64*32 + 64*64)*2 + 576*4)

__global__ __launch_bounds__(NTH)
void cpd_conv3d_fused_fb(const float* __restrict__ x,
                         const float* __restrict__ Ukh,
                         const float* __restrict__ Ukw,
                         const float* __restrict__ Ukd,
                         const float* __restrict__ Ucin,
                         const float* __restrict__ Uco,
                         const float* __restrict__ bias,
                         float* __restrict__ out)
{
    extern __shared__ char smem[];
    short* xs   = (short*)smem;
    short* t0   = xs   + NPADP*32;
    short* t1   = t0   + NPADP*32;
    short* uct  = t1   + 432*32;
    short* ucot = uct  + 64*32;
    float* ukf  = (float*)(ucot + 64*64);

    const int tid  = threadIdx.x;
    const int lane = tid & 63;
    const int wv   = tid >> 6;
    const int l15  = lane & 15;
    const int quad = lane >> 4;
    const int rg   = tid & 3;

    const int bid = blockIdx.x;
    const int dt = bid & 3, wt = (bid >> 2) & 15, ht = (bid >> 6) & 15, b = bid >> 10;
    const int h0 = ht * 4, w0 = wt * 4, d0 = dt * 16;

    for (int i = tid; i < 576; i += NTH) {
        float v = (i < 192) ? Ukh[i] : (i < 384 ? Ukw[i - 192] : Ukd[i - 384]);
        ukf[i] = v;
    }
    for (int i = tid; i < 2048; i += NTH) {
        int r = i >> 5, c = i & 31;
        uct[i] = f2b(Ucin[c * 64 + r]);
    }
    for (int i = tid; i < 4096; i += NTH) {
        int co = i >> 6, r = i & 63;
        ucot[i] = f2b(Uco[r * 64 + co]);
    }
    for (int i = tid; i < NPADP * 32; i += NTH) {
        int pp = i >> 5, c = i & 31;
        float v = 0.f;
        if (pp < 648) {
            int ph = pp / 108, rem = pp - ph * 108;
            int pw = rem / 18, pd = rem - pw * 18;
            int gh = h0 + ph - 1, gw = w0 + pw - 1, gd = d0 + pd - 1;
            if ((unsigned)gh < 64u && (unsigned)gw < 64u && (unsigned)gd < 64u)
                v = x[((long)(b * 32 + c) << 18) + (gh << 12) + (gw << 6) + gd];
        }
        xs[i] = f2b(v);
    }
    __syncthreads();

    f32x4 acc[8] = {};

    for (int pass = 0; pass < 2; ++pass) {
        const int rbase = pass * 32;
        {
            const int nt = wv & 1;
            short8 bfrag = *(const short8*)&uct[(rbase + nt * 16 + l15) * 32 + quad * 8];
            for (int mt = (wv >> 1); mt <= 40; mt += 4) {
                short8 afrag = *(const short8*)&xs[(mt * 16 + l15) * 32 + quad * 8];
                f32x4 c = {};
                c = __builtin_amdgcn_mfma_f32_16x16x32_bf16(afrag, bfrag, c, 0, 0, 0);
                const int col = nt * 16 + l15;
#pragma unroll
                for (int i2 = 0; i2 < 4; ++i2)
                    t0[(mt * 16 + quad * 4 + i2) * 32 + col] = f2b(c[i2]);
            }
        }
        __syncthreads();
        {
            float wh[3][8];
#pragma unroll
            for (int k = 0; k < 3; ++k) {
                const float4* pp_ = (const float4*)&ukf[k * 64 + rbase + rg * 8];
                float4 u0 = pp_[0], u1 = pp_[1];
                wh[k][0]=u0.x; wh[k][1]=u0.y; wh[k][2]=u0.z; wh[k][3]=u0.w;
                wh[k][4]=u1.x; wh[k][5]=u1.y; wh[k][6]=u1.z; wh[k][7]=u1.w;
            }
            for (int item = tid; item < 1728; item += NTH) {
                int q = item >> 2;
                float v[8] = {};
#pragma unroll
                for (int k = 0; k < 3; ++k) {
                    short8 sv = *(const short8*)&t0[(q + k * 108) * 32 + rg * 8];
#pragma unroll
                    for (int j = 0; j < 8; ++j) v[j] += wh[k][j] * b2f(sv[j]);
                }
                short8 o;
#pragma unroll
                for (int j = 0; j < 8; ++j) o[j] = f2b(v[j]);
                *(short8*)&t1[q * 32 + rg * 8] = o;
            }
        }
        __syncthreads();
        {
            float ww[3][8];
#pragma unroll
            for (int k = 0; k < 3; ++k) {
                const float4* pp_ = (const float4*)&ukf[(3 + k) * 64 + rbase + rg * 8];
                float4 u0 = pp_[0], u1 = pp_[1];
                ww[k][0]=u0.x; ww[k][1]=u0.y; ww[k][2]=u0.z; ww[k][3]=u0.w;
                ww[k][4]=u1.x; ww[k][5]=u1.y; ww[k][6]=u1.z; ww[k][7]=u1.w;
            }
            for (int item = tid; item < 1152; item += NTH) {
                int q2 = item >> 2;
                int oh = q2 / 72;
                int src = q2 + oh * 36;
                float v[8] = {};
#pragma unroll
                for (int k = 0; k < 3; ++k) {
                    short8 sv = *(const short8*)&t1[(src + k * 18) * 32 + rg * 8];
#pragma unroll
                    for (int j = 0; j < 8; ++j) v[j] += ww[k][j] * b2f(sv[j]);
                }
                short8 o;
#pragma unroll
                for (int j = 0; j < 8; ++j) o[j] = f2b(v[j]);
                *(short8*)&t0[q2 * 32 + rg * 8] = o;
            }
        }
        __syncthreads();
        {
            float wd[3][8];
#pragma unroll
            for (int k = 0; k < 3; ++k) {
                const float4* pp_ = (const float4*)&ukf[(6 + k) * 64 + rbase + rg * 8];
                float4 u0 = pp_[0], u1 = pp_[1];
                wd[k][0]=u0.x; wd[k][1]=u0.y; wd[k][2]=u0.z; wd[k][3]=u0.w;
                wd[k][4]=u1.x; wd[k][5]=u1.y; wd[k][6]=u1.z; wd[k][7]=u1.w;
            }
            for (int item = tid; item < 1024; item += NTH) {
                int pq = item >> 2;
                int src = pq + (pq >> 4) * 2;
                float v[8] = {};
#pragma unroll
                for (int k = 0; k < 3; ++k) {
                    short8 sv = *(const short8*)&t0[(src + k) * 32 + rg * 8];
#pragma unroll
                    for (int j = 0; j < 8; ++j) v[j] += wd[k][j] * b2f(sv[j]);
                }
                short8 o;
#pragma unroll
                for (int j = 0; j < 8; ++j) o[j] = f2b(v[j]);
                *(short8*)&t1[pq * 32 + rg * 8] = o;
            }
        }
        __syncthreads();
        {
            short8 bfr[4];
#pragma unroll
            for (int nt = 0; nt < 4; ++nt)
                bfr[nt] = *(const short8*)&ucot[(nt * 16 + l15) * 64 + rbase + quad * 8];
#pragma unroll
            for (int i = 0; i < 8; ++i) {
                int mt = wv * 2 + (i >> 2), nt = i & 3;
                short8 afr = *(const short8*)&t1[(mt * 16 + l15) * 32 + quad * 8];
                acc[i] = __builtin_amdgcn_mfma_f32_16x16x32_bf16(afr, bfr[nt], acc[i], 0, 0, 0);
            }
        }
    }

#pragma unroll
    for (int i = 0; i < 8; ++i) {
        int mt = wv * 2 + (i >> 2), nt = i & 3;
        int co = nt * 16 + l15;
        int oh = mt >> 2, ow = mt & 3;
        float bs = bias[co];
        float4 o4;
        o4.x = acc[i][0] + bs; o4.y = acc[i][1] + bs;
        o4.z = acc[i][2] + bs; o4.w = acc[i][3] + bs;
        long addr = ((long)(b * 64 + co) << 18) + ((long)(h0 + oh) << 12)
                  + ((w0 + ow) << 6) + (d0 + quad * 4);
        *(float4*)&out[addr] = o4;
    }
}

extern "C" void kernel_launch(void* const* d_in, const int* in_sizes, int n_in,
                              void* d_out, int out_size, void* d_ws, size_t ws_size,
                              hipStream_t stream) {
    const float* x    = (const float*)d_in[0];
    const float* Ukh  = (const float*)d_in[1];
    const float* Ukw  = (const float*)d_in[2];
    const float* Ukd  = (const float*)d_in[3];
    const float* Ucin = (const float*)d_in[4];
    const float* Uco  = (const float*)d_in[5];
    const float* bias = (const float*)d_in[6];
    float* out = (float*)d_out;

    const size_t needT = (size_t)2 * 262144 * 64 * 2;         // 64 MiB for t
    const size_t needM = (4096 + 2048 + 12288) * 2;           // 36 KiB weights
    if (ws_size >= needT + needM) {
        short* t     = (short*)d_ws;
        short* ucotT = (short*)((char*)d_ws + needT);
        short* ucinT = ucotT + 4096;
        short* gk    = ucinT + 2048;
        k0_prep<<<288, 64, 0, stream>>>(Uco, Ucin, Ukd, ucotT, ucinT, gk);
        k1_channel<<<2048, 256, 0, stream>>>(x, Ucin, ucinT, t);
        k2_conv_gemm_gk<<<8192, 256, 0, stream>>>(t, Ukh, Ukw, bias, gk, out);
    } else if (ws_size >= needT) {
        short* t = (short*)d_ws;
        k1_channel<<<2048, 256, 0, stream>>>(x, Ucin, nullptr, t);
        k2_conv_gemm<<<8192, 256, 0, stream>>>(t, Ukh, Ukw, Ukd, Uco, bias, nullptr, out);
    } else {
        (void)hipFuncSetAttribute((const void*)cpd_conv3d_fused_fb,
                                  hipFuncAttributeMaxDynamicSharedMemorySize,
                                  SMEM_BYTES);
        cpd_conv3d_fused_fb<<<2048, NTH, SMEM_BYTES, stream>>>(
            x, Ukh, Ukw, Ukd, Ucin, Uco, bias, out);
    }
}

// Round 6
// 262.782 us; speedup vs baseline: 1.0586x; 1.0586x over previous
//
#include <hip/hip_runtime.h>
#include <hip/hip_bf16.h>

typedef __attribute__((ext_vector_type(8))) short short8;
typedef __attribute__((ext_vector_type(4))) float f32x4;

// bf16 helpers. Conversion goes through the HIP intrinsics so the compiler
// emits hardware v_cvt_pk_bf16_f32 (1 inst / 2 values) instead of our old
// 4-8 VALU-op manual RNE sequence (m240: scalar casts > hand-written asm).
__device__ __forceinline__ float b2f(short s) {
    return __uint_as_float(((unsigned int)(unsigned short)s) << 16);
}
__device__ __forceinline__ float b2f_lo(unsigned u) {      // low bf16 of dword
    return __uint_as_float(u << 16);
}
__device__ __forceinline__ float b2f_hi(unsigned u) {      // high bf16: 1 op
    return __uint_as_float(u & 0xffff0000u);
}
__device__ __forceinline__ short f2b(float f) {
    union { __hip_bfloat16 h; short s; } cv;
    cv.h = __float2bfloat16(f);
    return cv.s;
}
__device__ __forceinline__ unsigned pack2(float a, float b) {
    union { __hip_bfloat162 h; unsigned u; } cv;
    cv.h = __float22bfloat162_rn(make_float2(a, b));
    return cv.u;
}

// ============================================================================
// K0: one-off prep (~2us).
//   ucotT[co][r] = bf16(Uco[r][co])   (4096)  - k2 staging without transpose
//   ucinT[r][c]  = bf16(Ucin[c][r])   (2048)  - k1 MFMA A-operand
// ============================================================================
__global__ __launch_bounds__(64)
void k0_prep(const float* __restrict__ Uco, const float* __restrict__ Ucin,
             short* __restrict__ ucotT, short* __restrict__ ucinT)
{
    const int i = blockIdx.x * 64 + threadIdx.x;    // 0..6143
    if (i < 4096) {
        int co = i >> 6, r = i & 63;
        ucotT[co * 64 + r] = f2b(Uco[r * 64 + co]);
    } else {
        int j = i - 4096;                           // 0..2047
        int r = j >> 5, c = j & 31;
        ucinT[r * 32 + c] = f2b(Ucin[c * 64 + r]);
    }
}

// ============================================================================
// K1: channel contraction as MFMA GEMM (round-4 structure, cvt_pk packing).
//   t[sp][r] = sum_c x[c][sp] * Ucin[c][r]
// ============================================================================
__global__ __launch_bounds__(256)
void k1_channel(const float* __restrict__ x,
                const float* __restrict__ Ucin,
                const short* __restrict__ ucinT_g,   // may be null
                short* __restrict__ t)
{
    __shared__ short xs[256 * 32];    // 16 KB  x^T tile, swizzled 16B slots
    __shared__ short uci[64 * 32];    //  4 KB  Ucin^T [r][c], linear

    const int tid = threadIdx.x;
    const int gp0 = blockIdx.x * 256;              // 2048 blocks, same b per block
    const int b   = gp0 >> 18;
    const int sp  = (gp0 & 262143) + tid;
    const float* xp = x + ((long)b << 23) + sp;

    if (ucinT_g) {
        ((short8*)uci)[tid] = ((const short8*)ucinT_g)[tid];
    } else {
        for (int i = tid; i < 2048; i += 256) {
            int r = i >> 5, c = i & 31;
            uci[i] = f2b(Ucin[c * 64 + r]);
        }
    }

    // stage x^T tile: thread owns sp-row tid; 32 coalesced load streams;
    // 16 cvt_pk builds 4 uint4 stores (was 32 manual f2b = ~130 VALU).
    {
        float v[32];
#pragma unroll
        for (int c = 0; c < 32; ++c) v[c] = xp[(long)c << 18];
        const int swz = (tid >> 1) & 3;
#pragma unroll
        for (int oct = 0; oct < 4; ++oct) {
            uint4 o;
            o.x = pack2(v[oct * 8 + 0], v[oct * 8 + 1]);
            o.y = pack2(v[oct * 8 + 2], v[oct * 8 + 3]);
            o.z = pack2(v[oct * 8 + 4], v[oct * 8 + 5]);
            o.w = pack2(v[oct * 8 + 6], v[oct * 8 + 7]);
            *(uint4*)&xs[tid * 32 + ((oct ^ swz) << 3)] = o;
        }
    }
    __syncthreads();

    const int lane = tid & 63, wv = tid >> 6;
    const int l15 = lane & 15, quad = lane >> 4;

    short8 afr[4];
#pragma unroll
    for (int mt = 0; mt < 4; ++mt)
        afr[mt] = *(const short8*)&uci[(mt * 16 + l15) * 32 + quad * 8];

    f32x4 acc[4][4] = {};
#pragma unroll
    for (int nt = 0; nt < 4; ++nt) {
        const int srow = wv * 64 + nt * 16 + l15;
        const int slot = quad ^ ((srow >> 1) & 3);
        short8 bfr = *(const short8*)&xs[srow * 32 + (slot << 3)];
#pragma unroll
        for (int mt = 0; mt < 4; ++mt)
            acc[mt][nt] = __builtin_amdgcn_mfma_f32_16x16x32_bf16(
                afr[mt], bfr, acc[mt][nt], 0, 0, 0);
    }

#pragma unroll
    for (int nt = 0; nt < 4; ++nt) {
        const int srow = wv * 64 + nt * 16 + l15;
        short* tb = t + ((size_t)(gp0 + srow) << 6);
#pragma unroll
        for (int mt = 0; mt < 4; ++mt) {
            uint2 o;
            o.x = pack2(acc[mt][nt][0], acc[mt][nt][1]);
            o.y = pack2(acc[mt][nt][2], acc[mt][nt][3]);
            *(uint2*)&tb[mt * 16 + quad * 4] = o;
        }
    }
}

// ============================================================================
// K2 (round-4 legacy structure, reverted from the gk fold which tripled
// phase-C LDS reads: 88us vs 73us; + cvt_pk packing + 1-op hi-half unpack).
//   phase A: hw-conv, software-pipelined 4 items/thread from 9 neighbor cols
//   phase B: d-conv -> p[64][72]
//   phase C: out GEMM M=64(d) N=64(co) K=64(r) + bias
// ============================================================================
__global__ __launch_bounds__(256)
void k2_conv_gemm(const short* __restrict__ t,
                  const float* __restrict__ Ukh,
                  const float* __restrict__ Ukw,
                  const float* __restrict__ Ukd,
                  const float* __restrict__ Uco,
                  const float* __restrict__ bias,
                  const short* __restrict__ ucotT,   // may be null
                  float* __restrict__ out)
{
    __shared__ short s[66 * 64];      //  8448 B
    __shared__ short p[64 * 72];      //  9216 B
    __shared__ short ucot[64 * 72];   //  9216 B   Uco^T, padded stride

    const int tid = threadIdx.x;

    const int bid  = blockIdx.x;              // 8192 = 2b * 64h * 64w
    const int slot = bid & 7;
    const int idx  = bid >> 3;                // 1024 per slot
    const int b    = idx >> 9;
    const int rem  = idx & 511;
    const int h    = slot * 8 + (rem >> 6);
    const int w    = rem & 63;

    const short* colp[9];
    bool valid[9];
#pragma unroll
    for (int kh = 0; kh < 3; ++kh) {
#pragma unroll
        for (int kw = 0; kw < 3; ++kw) {
            int hh = h + kh - 1, ww = w + kw - 1;
            bool v = ((unsigned)hh < 64u) && ((unsigned)ww < 64u);
            valid[kh * 3 + kw] = v;
            long base = v ? ((long)(b * 262144 + hh * 4096 + ww * 64) << 6) : 0;
            colp[kh * 3 + kw] = t + base;
        }
    }

    // stage Uco^T
    if (ucotT) {
        for (int i = tid; i < 512; i += 256) {
            int co = i >> 3, rb = i & 7;
            short8 v = *(const short8*)&ucotT[co * 64 + rb * 8];
            *(short8*)&ucot[co * 72 + rb * 8] = v;
        }
    } else {
        for (int i = tid; i < 4096; i += 256) {
            int r = i >> 6, co = i & 63;
            ucot[co * 72 + r] = f2b(Uco[i]);
        }
    }

    // ---- phase A: hw-conv. thread owns r-quad rq (fixed), iterates sd ----
    const int rq = tid & 15;                  // r = 4*rq .. 4*rq+3
    float4 W[9];
    {
        float4 a[3], c[3];
#pragma unroll
        for (int k = 0; k < 3; ++k) {
            a[k] = *(const float4*)&Ukh[k * 64 + 4 * rq];
            c[k] = *(const float4*)&Ukw[k * 64 + 4 * rq];
        }
#pragma unroll
        for (int kh = 0; kh < 3; ++kh)
#pragma unroll
            for (int kw = 0; kw < 3; ++kw) {
                int kk = kh * 3 + kw;
                float m = valid[kk] ? 1.f : 0.f;
                W[kk].x = a[kh].x * c[kw].x * m;
                W[kk].y = a[kh].y * c[kw].y * m;
                W[kk].z = a[kh].z * c[kw].z * m;
                W[kk].w = a[kh].w * c[kw].w * m;
            }
    }

    // zero edge rows sd=0 (d=-1) and sd=65 (d=64)
    if (tid < 32) {
        int sd = (tid < 16) ? 0 : 65;
        int rr = tid & 15;
        uint2 z; z.x = 0u; z.y = 0u;
        *(uint2*)&s[sd * 64 + 4 * rr] = z;
    }

    // main: 1024 in-bounds items = exactly 4/thread, software-pipelined
    {
        const int off0 = (tid >> 4) * 64 + 4 * rq;
        uint2 cur[9];
#pragma unroll
        for (int kk = 0; kk < 9; ++kk)
            cur[kk] = *(const uint2*)(colp[kk] + off0);

#pragma unroll
        for (int j = 0; j < 4; ++j) {
            uint2 nxt[9];
            if (j < 3) {
#pragma unroll
                for (int kk = 0; kk < 9; ++kk)
                    nxt[kk] = *(const uint2*)(colp[kk] + off0 + 1024 * (j + 1));
            }
            float a0 = 0.f, a1 = 0.f, a2 = 0.f, a3 = 0.f;
#pragma unroll
            for (int kk = 0; kk < 9; ++kk) {
                uint2 uu = cur[kk];
                a0 += W[kk].x * b2f_lo(uu.x);
                a1 += W[kk].y * b2f_hi(uu.x);
                a2 += W[kk].z * b2f_lo(uu.y);
                a3 += W[kk].w * b2f_hi(uu.y);
            }
            int sd = 1 + (tid >> 4) + 16 * j;
            uint2 o; o.x = pack2(a0, a1); o.y = pack2(a2, a3);
            *(uint2*)&s[sd * 64 + 4 * rq] = o;
            if (j < 3) {
#pragma unroll
                for (int kk = 0; kk < 9; ++kk) cur[kk] = nxt[kk];
            }
        }
    }
    __syncthreads();

    // ---- phase B: d-conv into p (stride 72) ----
    {
        float4 Wd[3];
#pragma unroll
        for (int k = 0; k < 3; ++k)
            Wd[k] = *(const float4*)&Ukd[k * 64 + 4 * rq];
        for (int u = tid; u < 64 * 16; u += 256) {
            int d = u >> 4;
            float a0 = 0.f, a1 = 0.f, a2 = 0.f, a3 = 0.f;
#pragma unroll
            for (int k = 0; k < 3; ++k) {
                uint2 uu = *(const uint2*)&s[(d + k) * 64 + 4 * rq];
                a0 += Wd[k].x * b2f_lo(uu.x);
                a1 += Wd[k].y * b2f_hi(uu.x);
                a2 += Wd[k].z * b2f_lo(uu.y);
                a3 += Wd[k].w * b2f_hi(uu.y);
            }
            uint2 o; o.x = pack2(a0, a1); o.y = pack2(a2, a3);
            *(uint2*)&p[d * 72 + 4 * rq] = o;
        }
    }
    __syncthreads();

    // ---- phase C: out GEMM + bias + store ----
    {
        const int lane = tid & 63, wv = tid >> 6;
        const int l15 = lane & 15, quad = lane >> 4;
        short8 afr0 = *(const short8*)&p[(wv * 16 + l15) * 72 + quad * 8];
        short8 afr1 = *(const short8*)&p[(wv * 16 + l15) * 72 + 32 + quad * 8];
        f32x4 acc[4] = {};
#pragma unroll
        for (int nt = 0; nt < 4; ++nt) {
            short8 b0 = *(const short8*)&ucot[(nt * 16 + l15) * 72 + quad * 8];
            short8 b1 = *(const short8*)&ucot[(nt * 16 + l15) * 72 + 32 + quad * 8];
            acc[nt] = __builtin_amdgcn_mfma_f32_16x16x32_bf16(afr0, b0, acc[nt], 0, 0, 0);
            acc[nt] = __builtin_amdgcn_mfma_f32_16x16x32_bf16(afr1, b1, acc[nt], 0, 0, 0);
        }
#pragma unroll
        for (int nt = 0; nt < 4; ++nt) {
            int co = nt * 16 + l15;
            float bs = bias[co];
            int d = wv * 16 + quad * 4;
            float4 o;
            o.x = acc[nt][0] + bs; o.y = acc[nt][1] + bs;
            o.z = acc[nt][2] + bs; o.w = acc[nt][3] + bs;
            long addr = ((long)(b * 64 + co) << 18) + (h << 12) + (w << 6) + d;
            *(float4*)&out[addr] = o;
        }
    }
}

// ============================================================================
// Fallback (fused kernel) if workspace is too small for t.
// ============================================================================
#define NTH 512
#define NPADP 656
#define SMEM_BYTES ((NPADP*32 + NPADP*32 + 432*32 + 64*32 + 64*64)*2 + 576*4)

__global__ __launch_bounds__(NTH)
void cpd_conv3d_fused_fb(const float* __restrict__ x,
                         const float* __restrict__ Ukh,
                         const float* __restrict__ Ukw,
                         const float* __restrict__ Ukd,
                         const float* __restrict__ Ucin,
                         const float* __restrict__ Uco,
                         const float* __restrict__ bias,
                         float* __restrict__ out)
{
    extern __shared__ char smem[];
    short* xs   = (short*)smem;
    short* t0   = xs   + NPADP*32;
    short* t1   = t0   + NPADP*32;
    short* uct  = t1   + 432*32;
    short* ucot = uct  + 64*32;
    float* ukf  = (float*)(ucot + 64*64);

    const int tid  = threadIdx.x;
    const int lane = tid & 63;
    const int wv   = tid >> 6;
    const int l15  = lane & 15;
    const int quad = lane >> 4;
    const int rg   = tid & 3;

    const int bid = blockIdx.x;
    const int dt = bid & 3, wt = (bid >> 2) & 15, ht = (bid >> 6) & 15, b = bid >> 10;
    const int h0 = ht * 4, w0 = wt * 4, d0 = dt * 16;

    for (int i = tid; i < 576; i += NTH) {
        float v = (i < 192) ? Ukh[i] : (i < 384 ? Ukw[i - 192] : Ukd[i - 384]);
        ukf[i] = v;
    }
    for (int i = tid; i < 2048; i += NTH) {
        int r = i >> 5, c = i & 31;
        uct[i] = f2b(Ucin[c * 64 + r]);
    }
    for (int i = tid; i < 4096; i += NTH) {
        int co = i >> 6, r = i & 63;
        ucot[i] = f2b(Uco[r * 64 + co]);
    }
    for (int i = tid; i < NPADP * 32; i += NTH) {
        int pp = i >> 5, c = i & 31;
        float v = 0.f;
        if (pp < 648) {
            int ph = pp / 108, rem = pp - ph * 108;
            int pw = rem / 18, pd = rem - pw * 18;
            int gh = h0 + ph - 1, gw = w0 + pw - 1, gd = d0 + pd - 1;
            if ((unsigned)gh < 64u && (unsigned)gw < 64u && (unsigned)gd < 64u)
                v = x[((long)(b * 32 + c) << 18) + (gh << 12) + (gw << 6) + gd];
        }
        xs[i] = f2b(v);
    }
    __syncthreads();

    f32x4 acc[8] = {};

    for (int pass = 0; pass < 2; ++pass) {
        const int rbase = pass * 32;
        {
            const int nt = wv & 1;
            short8 bfrag = *(const short8*)&uct[(rbase + nt * 16 + l15) * 32 + quad * 8];
            for (int mt = (wv >> 1); mt <= 40; mt += 4) {
                short8 afrag = *(const short8*)&xs[(mt * 16 + l15) * 32 + quad * 8];
                f32x4 c = {};
                c = __builtin_amdgcn_mfma_f32_16x16x32_bf16(afrag, bfrag, c, 0, 0, 0);
                const int col = nt * 16 + l15;
#pragma unroll
                for (int i2 = 0; i2 < 4; ++i2)
                    t0[(mt * 16 + quad * 4 + i2) * 32 + col] = f2b(c[i2]);
            }
        }
        __syncthreads();
        {
            float wh[3][8];
#pragma unroll
            for (int k = 0; k < 3; ++k) {
                const float4* pp_ = (const float4*)&ukf[k * 64 + rbase + rg * 8];
                float4 u0 = pp_[0], u1 = pp_[1];
                wh[k][0]=u0.x; wh[k][1]=u0.y; wh[k][2]=u0.z; wh[k][3]=u0.w;
                wh[k][4]=u1.x; wh[k][5]=u1.y; wh[k][6]=u1.z; wh[k][7]=u1.w;
            }
            for (int item = tid; item < 1728; item += NTH) {
                int q = item >> 2;
                float v[8] = {};
#pragma unroll
                for (int k = 0; k < 3; ++k) {
                    short8 sv = *(const short8*)&t0[(q + k * 108) * 32 + rg * 8];
#pragma unroll
                    for (int j = 0; j < 8; ++j) v[j] += wh[k][j] * b2f(sv[j]);
                }
                short8 o;
#pragma unroll
                for (int j = 0; j < 8; ++j) o[j] = f2b(v[j]);
                *(short8*)&t1[q * 32 + rg * 8] = o;
            }
        }
        __syncthreads();
        {
            float ww[3][8];
#pragma unroll
            for (int k = 0; k < 3; ++k) {
                const float4* pp_ = (const float4*)&ukf[(3 + k) * 64 + rbase + rg * 8];
                float4 u0 = pp_[0], u1 = pp_[1];
                ww[k][0]=u0.x; ww[k][1]=u0.y; ww[k][2]=u0.z; ww[k][3]=u0.w;
                ww[k][4]=u1.x; ww[k][5]=u1.y; ww[k][6]=u1.z; ww[k][7]=u1.w;
            }
            for (int item = tid; item < 1152; item += NTH) {
                int q2 = item >> 2;
                int oh = q2 / 72;
                int src = q2 + oh * 36;
                float v[8] = {};
#pragma unroll
                for (int k = 0; k < 3; ++k) {
                    short8 sv = *(const short8*)&t1[(src + k * 18) * 32 + rg * 8];
#pragma unroll
                    for (int j = 0; j < 8; ++j) v[j] += ww[k][j] * b2f(sv[j]);
                }
                short8 o;
#pragma unroll
                for (int j = 0; j < 8; ++j) o[j] = f2b(v[j]);
                *(short8*)&t0[q2 * 32 + rg * 8] = o;
            }
        }
        __syncthreads();
        {
            float wd[3][8];
#pragma unroll
            for (int k = 0; k < 3; ++k) {
                const float4* pp_ = (const float4*)&ukf[(6 + k) * 64 + rbase + rg * 8];
                float4 u0 = pp_[0], u1 = pp_[1];
                wd[k][0]=u0.x; wd[k][1]=u0.y; wd[k][2]=u0.z; wd[k][3]=u0.w;
                wd[k][4]=u1.x; wd[k][5]=u1.y; wd[k][6]=u1.z; wd[k][7]=u1.w;
            }
            for (int item = tid; item < 1024; item += NTH) {
                int pq = item >> 2;
                int src = pq + (pq >> 4) * 2;
                float v[8] = {};
#pragma unroll
                for (int k = 0; k < 3; ++k) {
                    short8 sv = *(const short8*)&t0[(src + k) * 32 + rg * 8];
#pragma unroll
                    for (int j = 0; j < 8; ++j) v[j] += wd[k][j] * b2f(sv[j]);
                }
                short8 o;
#pragma unroll
                for (int j = 0; j < 8; ++j) o[j] = f2b(v[j]);
                *(short8*)&t1[pq * 32 + rg * 8] = o;
            }
        }
        __syncthreads();
        {
            short8 bfr[4];
#pragma unroll
            for (int nt = 0; nt < 4; ++nt)
                bfr[nt] = *(const short8*)&ucot[(nt * 16 + l15) * 64 + rbase + quad * 8];
#pragma unroll
            for (int i = 0; i < 8; ++i) {
                int mt = wv * 2 + (i >> 2), nt = i & 3;
                short8 afr = *(const short8*)&t1[(mt * 16 + l15) * 32 + quad * 8];
                acc[i] = __builtin_amdgcn_mfma_f32_16x16x32_bf16(afr, bfr[nt], acc[i], 0, 0, 0);
            }
        }
    }

#pragma unroll
    for (int i = 0; i < 8; ++i) {
        int mt = wv * 2 + (i >> 2), nt = i & 3;
        int co = nt * 16 + l15;
        int oh = mt >> 2, ow = mt & 3;
        float bs = bias[co];
        float4 o4;
        o4.x = acc[i][0] + bs; o4.y = acc[i][1] + bs;
        o4.z = acc[i][2] + bs; o4.w = acc[i][3] + bs;
        long addr = ((long)(b * 64 + co) << 18) + ((long)(h0 + oh) << 12)
                  + ((w0 + ow) << 6) + (d0 + quad * 4);
        *(float4*)&out[addr] = o4;
    }
}

extern "C" void kernel_launch(void* const* d_in, const int* in_sizes, int n_in,
                              void* d_out, int out_size, void* d_ws, size_t ws_size,
                              hipStream_t stream) {
    const float* x    = (const float*)d_in[0];
    const float* Ukh  = (const float*)d_in[1];
    const float* Ukw  = (const float*)d_in[2];
    const float* Ukd  = (const float*)d_in[3];
    const float* Ucin = (const float*)d_in[4];
    const float* Uco  = (const float*)d_in[5];
    const float* bias = (const float*)d_in[6];
    float* out = (float*)d_out;

    const size_t needT = (size_t)2 * 262144 * 64 * 2;   // 64 MiB for t (bf16)
    const size_t needM = (4096 + 2048) * 2;             // 12 KiB ucotT + ucinT
    if (ws_size >= needT) {
        short* t = (short*)d_ws;
        short* ucotT = nullptr;
        short* ucinT = nullptr;
        if (ws_size >= needT + needM) {
            ucotT = (short*)((char*)d_ws + needT);
            ucinT = ucotT + 4096;
            k0_prep<<<96, 64, 0, stream>>>(Uco, Ucin, ucotT, ucinT);
        }
        k1_channel<<<2048, 256, 0, stream>>>(x, Ucin, ucinT, t);
        k2_conv_gemm<<<8192, 256, 0, stream>>>(t, Ukh, Ukw, Ukd, Uco, bias, ucotT, out);
    } else {
        (void)hipFuncSetAttribute((const void*)cpd_conv3d_fused_fb,
                                  hipFuncAttributeMaxDynamicSharedMemorySize,
                                  SMEM_BYTES);
        cpd_conv3d_fused_fb<<<2048, NTH, SMEM_BYTES, stream>>>(
            x, Ukh, Ukw, Ukd, Ucin, Uco, bias, out);
    }
}